// Round 2
// baseline (659.778 us; speedup 1.0000x reference)
//
#include <hip/hip_runtime.h>
#include <hip/hip_bf16.h>

#define N_IN 200000
#define N_OUT 200000
#define K_VOL 27
#define M_PAIRS 100000
#define C_IN 64
#define C_OUT 64
#define NPAIRS (K_VOL * M_PAIRS)   // 2,700,000

#define MTILE 64
#define LDS_PAD 72   // 64 + 8 bf16 -> 144B row stride, breaks 32-bank aliasing, keeps 16B align

// ---- workspace layout (bytes) ----
#define FEATS_OFF   0UL
#define FEATS_BYTES (200000UL * 64 * 2)            // 25,600,000
#define WT_OFF      (FEATS_OFF + FEATS_BYTES)      // 25,600,000
#define WT_BYTES    (27UL * 64 * 64 * 2)           // 221,184
#define OFFS_OFF    (WT_OFF + WT_BYTES)            // 25,821,184
#define OFFS_BYTES  (800064UL)                     // 200001 ints, padded
#define CNT_OFF     (OFFS_OFF + OFFS_BYTES)        // counts, then reused as cursor
#define CNT_BYTES   (800000UL)
#define BSUM_OFF    (CNT_OFF + CNT_BYTES)
#define BSUM_BYTES  (4096UL)
#define POS_OFF     (BSUM_OFF + BSUM_BYTES)
#define POS_BYTES   (10800064UL)                   // 2.7M ints, padded
#define CONTRIB_OFF ((POS_OFF + POS_BYTES + 255UL) & ~255UL)
#define CONTRIB_BYTES (2700000UL * 64 * 2)         // 345,600,000
#define WS_NEEDED   (CONTRIB_OFF + CONTRIB_BYTES)  // ~383.9 MB

#define SCAN_NB 782  // ceil(200001/256)

typedef __attribute__((ext_vector_type(4))) float floatx4;
typedef __attribute__((ext_vector_type(8))) short shortx8;

static __device__ __forceinline__ ushort f32_to_bf16(float f) {
    union { float f; unsigned int u; } x; x.f = f;
    unsigned int u = x.u;
    u += 0x7FFFu + ((u >> 16) & 1u);   // round-to-nearest-even
    return (ushort)(u >> 16);
}
static __device__ __forceinline__ float bf16_to_f32(ushort u) {
    union { unsigned int ui; float f; } cv; cv.ui = ((unsigned int)u) << 16;
    return cv.f;
}

// ---------------- prep ----------------
__global__ void cvt_feats_kernel(const float* __restrict__ src, ushort* __restrict__ dst, int n4) {
    int i = blockIdx.x * blockDim.x + threadIdx.x;
    if (i >= n4) return;
    float4 v = ((const float4*)src)[i];
    ushort4 o;
    o.x = f32_to_bf16(v.x); o.y = f32_to_bf16(v.y);
    o.z = f32_to_bf16(v.z); o.w = f32_to_bf16(v.w);
    ((ushort4*)dst)[i] = o;
}

// kernel[k][c][o] fp32 -> wt[k][o][c] bf16
__global__ void cvt_wt_kernel(const float* __restrict__ w, ushort* __restrict__ wt) {
    int idx = blockIdx.x * blockDim.x + threadIdx.x;
    if (idx >= K_VOL * C_IN * C_OUT) return;
    int k   = idx >> 12;
    int rem = idx & 4095;
    int c   = rem >> 6;
    int o   = rem & 63;
    wt[(k << 12) + (o << 6) + c] = f32_to_bf16(w[idx]);
}

// ---------------- CSR build ----------------
__global__ void hist_kernel(const int* __restrict__ omap, int* __restrict__ counts) {
    int p = blockIdx.x * blockDim.x + threadIdx.x;
    if (p >= NPAIRS) return;
    atomicAdd(&counts[omap[p]], 1);
}

__global__ void scan1_kernel(const int* __restrict__ counts, int* __restrict__ bsum) {
    __shared__ int sd[256];
    int tid = threadIdx.x;
    int i = blockIdx.x * 256 + tid;
    sd[tid] = (i < N_OUT) ? counts[i] : 0;
    __syncthreads();
    for (int s = 128; s > 0; s >>= 1) {
        if (tid < s) sd[tid] += sd[tid + s];
        __syncthreads();
    }
    if (tid == 0) bsum[blockIdx.x] = sd[0];
}

__global__ void scan2_kernel(int* __restrict__ bsum) {
    __shared__ int sd[1024];
    int tid = threadIdx.x;
    int v = (tid < SCAN_NB) ? bsum[tid] : 0;
    sd[tid] = v;
    __syncthreads();
    for (int off = 1; off < 1024; off <<= 1) {
        int t = (tid >= off) ? sd[tid - off] : 0;
        __syncthreads();
        sd[tid] += t;
        __syncthreads();
    }
    if (tid < SCAN_NB) bsum[tid] = sd[tid] - v;  // exclusive
}

// writes offsets[i] (i<=N_OUT) and cursor[i]=offsets[i] (cursor aliases counts)
__global__ void scan3_kernel(int* __restrict__ counts_cursor, const int* __restrict__ bsum,
                             int* __restrict__ offsets) {
    __shared__ int sd[256];
    int tid = threadIdx.x;
    int i = blockIdx.x * 256 + tid;
    int v = (i < N_OUT) ? counts_cursor[i] : 0;
    sd[tid] = v;
    __syncthreads();
    for (int off = 1; off < 256; off <<= 1) {
        int t = (tid >= off) ? sd[tid - off] : 0;
        __syncthreads();
        sd[tid] += t;
        __syncthreads();
    }
    int excl = sd[tid] - v + bsum[blockIdx.x];
    if (i <= N_OUT) offsets[i] = excl;
    if (i < N_OUT) counts_cursor[i] = excl;   // cursor copy (all reads done above)
}

__global__ void fill_kernel(const int* __restrict__ omap, int* __restrict__ cursor,
                            int* __restrict__ pos_of_pair) {
    int p = blockIdx.x * blockDim.x + threadIdx.x;
    if (p >= NPAIRS) return;
    int o = omap[p];
    pos_of_pair[p] = atomicAdd(&cursor[o], 1);
}

// ---------------- phase B: gather -> MFMA -> scatter rows into CSR slots ----------------
__launch_bounds__(256, 4)
__global__ void gemm_scatter_kernel(const ushort* __restrict__ feats,  // [N_IN][64] bf16
                                    const ushort* __restrict__ wt,     // [K][o][c] bf16
                                    const int* __restrict__ imap,
                                    const int* __restrict__ pos_of_pair,
                                    ushort* __restrict__ contrib) {    // [NPAIRS][64] bf16, CSR order
    __shared__ ushort Asm[MTILE * LDS_PAD];
    __shared__ ushort Wsm[C_OUT * LDS_PAD];
    __shared__ ushort Csm[MTILE * LDS_PAD];
    __shared__ int pos_s[MTILE];

    const int k   = blockIdx.y;
    const int m0  = blockIdx.x * MTILE;
    const int tid = threadIdx.x;
    const int kM  = k * M_PAIRS;

    #pragma unroll
    for (int p = 0; p < 2; ++p) {
        int cid = tid + p * 256;
        int row = cid >> 3;
        int ch  = cid & 7;
        *(shortx8*)&Wsm[row * LDS_PAD + ch * 8] =
            *(const shortx8*)&wt[(k << 12) + row * 64 + ch * 8];
    }
    #pragma unroll
    for (int p = 0; p < 2; ++p) {
        int cid = tid + p * 256;
        int row = cid >> 3;
        int ch  = cid & 7;
        int m   = m0 + row;
        shortx8 v = {0, 0, 0, 0, 0, 0, 0, 0};
        if (m < M_PAIRS) {
            int g = imap[kM + m];
            v = *(const shortx8*)&feats[(g << 6) + ch * 8];
        }
        *(shortx8*)&Asm[row * LDS_PAD + ch * 8] = v;
    }
    if (tid < MTILE) {
        int m = m0 + tid;
        pos_s[tid] = (m < M_PAIRS) ? pos_of_pair[kM + m] : -1;
    }
    __syncthreads();

    const int wave = tid >> 6;
    const int lane = tid & 63;
    const int quad = lane >> 4;
    const int l16  = lane & 15;
    const int rbase = wave * 16;

    // A[m=l16][k=quad*8+j]
    const shortx8 a0 = *(const shortx8*)&Asm[(rbase + l16) * LDS_PAD + quad * 8];
    const shortx8 a1 = *(const shortx8*)&Asm[(rbase + l16) * LDS_PAD + 32 + quad * 8];

    #pragma unroll
    for (int ct = 0; ct < 4; ++ct) {
        const shortx8 b0 = *(const shortx8*)&Wsm[(ct * 16 + l16) * LDS_PAD + quad * 8];
        const shortx8 b1 = *(const shortx8*)&Wsm[(ct * 16 + l16) * LDS_PAD + 32 + quad * 8];
        floatx4 acc = {0.f, 0.f, 0.f, 0.f};
        acc = __builtin_amdgcn_mfma_f32_16x16x32_bf16(a0, b0, acc, 0, 0, 0);
        acc = __builtin_amdgcn_mfma_f32_16x16x32_bf16(a1, b1, acc, 0, 0, 0);
        const int col = ct * 16 + l16;
        #pragma unroll
        for (int r = 0; r < 4; ++r) {
            int rl = rbase + quad * 4 + r;           // C row = quad*4 + reg
            Csm[rl * LDS_PAD + col] = f32_to_bf16(acc[r]);
        }
    }
    __syncthreads();

    // scatter rows (128B each, full cache lines, no RMW)
    #pragma unroll
    for (int p = 0; p < 2; ++p) {
        int cid = tid + p * 256;
        int row = cid >> 3;
        int ch  = cid & 7;
        int pos = pos_s[row];
        if (pos >= 0) {
            *(shortx8*)&contrib[(size_t)pos * 64 + ch * 8] =
                *(const shortx8*)&Csm[row * LDS_PAD + ch * 8];
        }
    }
}

// ---------------- phase C: sequential segmented reduce + bias ----------------
__launch_bounds__(256, 4)
__global__ void reduce_kernel(const ushort* __restrict__ contrib,
                              const int* __restrict__ offsets,
                              const float* __restrict__ bias,
                              float* __restrict__ out) {
    int wave = threadIdx.x >> 6;
    int lane = threadIdx.x & 63;
    int row  = blockIdx.x * 4 + wave;
    if (row >= N_OUT) return;
    int beg = offsets[row];
    int end = offsets[row + 1];
    float acc = bias[lane];
    int j = beg;
    for (; j + 2 <= end; j += 2) {
        ushort u0 = contrib[(size_t)j * 64 + lane];
        ushort u1 = contrib[(size_t)(j + 1) * 64 + lane];
        acc += bf16_to_f32(u0);
        acc += bf16_to_f32(u1);
    }
    if (j < end) acc += bf16_to_f32(contrib[(size_t)j * 64 + lane]);
    out[(size_t)row * 64 + lane] = acc;
}

// ---------------- fallback (round-1 push path) ----------------
__global__ void init_bias_kernel(const float* __restrict__ bias, float* __restrict__ out, int n4) {
    int i = blockIdx.x * blockDim.x + threadIdx.x;
    if (i >= n4) return;
    int c = (i * 4) & 63;
    float4 b = *(const float4*)(bias + c);
    ((float4*)out)[i] = b;
}

__launch_bounds__(256, 4)
__global__ void spconv_push_kernel(const ushort* __restrict__ feats,
                                   const ushort* __restrict__ wt,
                                   const int* __restrict__ imap,
                                   const int* __restrict__ omap,
                                   float* __restrict__ out) {
    __shared__ ushort Asm[MTILE * LDS_PAD];
    __shared__ ushort Wsm[C_OUT * LDS_PAD];
    __shared__ int omap_s[MTILE];

    const int k   = blockIdx.y;
    const int m0  = blockIdx.x * MTILE;
    const int tid = threadIdx.x;
    const int kM  = k * M_PAIRS;

    #pragma unroll
    for (int p = 0; p < 2; ++p) {
        int cid = tid + p * 256;
        int row = cid >> 3;
        int ch  = cid & 7;
        *(shortx8*)&Wsm[row * LDS_PAD + ch * 8] =
            *(const shortx8*)&wt[(k << 12) + row * 64 + ch * 8];
    }
    #pragma unroll
    for (int p = 0; p < 2; ++p) {
        int cid = tid + p * 256;
        int row = cid >> 3;
        int ch  = cid & 7;
        int m   = m0 + row;
        shortx8 v = {0, 0, 0, 0, 0, 0, 0, 0};
        if (m < M_PAIRS) {
            int g = imap[kM + m];
            v = *(const shortx8*)&feats[(g << 6) + ch * 8];
        }
        *(shortx8*)&Asm[row * LDS_PAD + ch * 8] = v;
    }
    if (tid < MTILE) {
        int m = m0 + tid;
        omap_s[tid] = (m < M_PAIRS) ? omap[kM + m] : -1;
    }
    __syncthreads();

    const int wave = tid >> 6;
    const int lane = tid & 63;
    const int quad = lane >> 4;
    const int l16  = lane & 15;
    const int rbase = wave * 16;

    const shortx8 a0 = *(const shortx8*)&Asm[(rbase + l16) * LDS_PAD + quad * 8];
    const shortx8 a1 = *(const shortx8*)&Asm[(rbase + l16) * LDS_PAD + 32 + quad * 8];

    #pragma unroll
    for (int ct = 0; ct < 4; ++ct) {
        const shortx8 b0 = *(const shortx8*)&Wsm[(ct * 16 + l16) * LDS_PAD + quad * 8];
        const shortx8 b1 = *(const shortx8*)&Wsm[(ct * 16 + l16) * LDS_PAD + 32 + quad * 8];
        floatx4 acc = {0.f, 0.f, 0.f, 0.f};
        acc = __builtin_amdgcn_mfma_f32_16x16x32_bf16(a0, b0, acc, 0, 0, 0);
        acc = __builtin_amdgcn_mfma_f32_16x16x32_bf16(a1, b1, acc, 0, 0, 0);
        const int col = ct * 16 + l16;
        #pragma unroll
        for (int r = 0; r < 4; ++r) {
            int rl = rbase + quad * 4 + r;
            int orow = omap_s[rl];
            if (orow >= 0) atomicAdd(&out[(orow << 6) + col], acc[r]);
        }
    }
}

extern "C" void kernel_launch(void* const* d_in, const int* in_sizes, int n_in,
                              void* d_out, int out_size, void* d_ws, size_t ws_size,
                              hipStream_t stream) {
    const float* in_feats = (const float*)d_in[0];
    const float* kernelw  = (const float*)d_in[1];
    const float* bias     = (const float*)d_in[2];
    const int*   imap     = (const int*)d_in[3];
    const int*   omap     = (const int*)d_in[4];
    float* out = (float*)d_out;

    char* ws = (char*)d_ws;
    ushort* feats_bf = (ushort*)(ws + FEATS_OFF);
    ushort* wt_bf    = (ushort*)(ws + WT_OFF);

    int n4 = N_IN * C_IN / 4;
    cvt_feats_kernel<<<(n4 + 255) / 256, 256, 0, stream>>>(in_feats, feats_bf, n4);
    cvt_wt_kernel<<<(K_VOL * C_IN * C_OUT + 255) / 256, 256, 0, stream>>>(kernelw, wt_bf);

    if (ws_size >= WS_NEEDED) {
        // -------- pull path: CSR build -> GEMM scatter -> segmented reduce --------
        int* offsets = (int*)(ws + OFFS_OFF);
        int* counts  = (int*)(ws + CNT_OFF);   // doubles as cursor after scan3
        int* bsum    = (int*)(ws + BSUM_OFF);
        int* pos     = (int*)(ws + POS_OFF);
        ushort* contrib = (ushort*)(ws + CONTRIB_OFF);

        hipMemsetAsync(counts, 0, CNT_BYTES, stream);
        hist_kernel<<<(NPAIRS + 255) / 256, 256, 0, stream>>>(omap, counts);
        scan1_kernel<<<SCAN_NB, 256, 0, stream>>>(counts, bsum);
        scan2_kernel<<<1, 1024, 0, stream>>>(bsum);
        scan3_kernel<<<SCAN_NB, 256, 0, stream>>>(counts, bsum, offsets);
        fill_kernel<<<(NPAIRS + 255) / 256, 256, 0, stream>>>(omap, counts, pos);

        dim3 grid((M_PAIRS + MTILE - 1) / MTILE, K_VOL);
        gemm_scatter_kernel<<<grid, 256, 0, stream>>>(feats_bf, wt_bf, imap, pos, contrib);

        reduce_kernel<<<(N_OUT + 3) / 4, 256, 0, stream>>>(contrib, offsets, bias, out);
    } else {
        // -------- fallback: round-1 push path --------
        int o4 = N_OUT * C_OUT / 4;
        init_bias_kernel<<<(o4 + 255) / 256, 256, 0, stream>>>(bias, out, o4);
        dim3 grid((M_PAIRS + MTILE - 1) / MTILE, K_VOL);
        spconv_push_kernel<<<grid, 256, 0, stream>>>(feats_bf, wt_bf, imap, omap, out);
    }
}